// Round 5
// baseline (497.873 us; speedup 1.0000x reference)
//
#include <hip/hip_runtime.h>
#include <math.h>

#define NV    49
#define NVP   52
#define Himg  256
#define Wimg  256
#define RW    240
#define RWH   (RW*RW)          // 57600
#define NPIX  (4*RWH)          // 230400
#define ROWF  (Wimg*3)         // 768 floats per image row
#define IMGF  (Himg*Wimg*3)    // 196608 floats per view image
#define NBLK  (NPIX/64)        // 3600 blocks (fused fallback)

// 4B-aligned wide vector loads (gfx950 global loads legal at dword align)
typedef float f4u __attribute__((ext_vector_type(4), aligned(4)));
typedef float f2u __attribute__((ext_vector_type(2), aligned(4)));
typedef float f4a __attribute__((ext_vector_type(4), aligned(16)));

// ===========================================================================
// SPLIT PATH
// Kernel A: one lane = one (view n, batch b, pixel). Barrier-free gather:
// memory latency hidden by 176k independent waves of TLP instead of
// per-wave pipelining (R0-R3 showed the fused structure cannot: dur*VALUBusy
// invariant ~130k cycles, VALUBusy pinned ~33% by the load->barrier convoy).
// Writes cl to clbuf[n*NPIX + gpix] (45 MB, L3-resident).
// ===========================================================================

__global__ __launch_bounds__(256) void cl_kernel(
    const float* __restrict__ pred, const float* __restrict__ x,
    float* __restrict__ clbuf, double* __restrict__ acc)
{
    const int tid = threadIdx.x;
    const int nb  = blockIdx.y;          // 0..195 = n*4 + b  (scalar)
    const int b   = nb & 3;
    const int n   = nb >> 2;
    const int u   = n / 7, v = n - u*7;

    int pix = blockIdx.x*256 + tid;      // 0..57599 within (b, view)
    int ry  = pix / RW;
    int rx  = pix - ry*RW;
    int yy  = 8 + ry, xx = 8 + rx;
    int pidx = (b*Himg + yy)*Wimg + xx;
    float p = pred[pidx];

    const float* xv    = x + (size_t)b * (49*IMGF);
    const float* cbase = xv + 24*IMGF + (yy*Wimg+xx)*3;
    f4u cv = *(const f4u*)cbase;         // center texel (always in-bounds)
    float c0 = cv.x, c1 = cv.y, c2 = cv.z;

    // x interpolant for this view's v
    float cx  = fminf(fmaxf((float)xx + p*(float)(v-3), 0.0f), 255.0f);
    float x0f = floorf(cx);
    float tx  = cx - x0f;
    int ix0   = (int)x0f;
    if (ix0 >= 255) { ix0 = 254; tx = 1.0f; }   // same bilinear result
    // y interpolant for this view's u
    float cy  = fminf(fmaxf((float)yy + p*(float)(u-3), 0.0f), 255.0f);
    float y0f = floorf(cy);
    float ty  = cy - y0f;
    int iy0   = (int)y0f;
    int iy1   = min(iy0+1, 255);

    const float* ib  = xv + n*IMGF;
    const float* s0p = ib + iy0*ROWF + ix0*3;
    const float* s1p = ib + iy1*ROWF + ix0*3;
    f4u a0 = *(const f4u*)s0p;  f2u a1 = *(const f2u*)(s0p + 4);
    f4u b0 = *(const f4u*)s1p;  f2u b1 = *(const f2u*)(s1p + 4);

    float s00 = a0.x, s01 = a0.y, s02 = a0.z;
    float s03 = a0.w, s04 = a1.x, s05 = a1.y;
    float s10 = b0.x, s11 = b0.y, s12 = b0.z;
    float s13 = b0.w, s14 = b1.x, s15 = b1.y;
    float h0 = s00 + tx*(s03-s00);
    float h1 = s01 + tx*(s04-s01);
    float h2 = s02 + tx*(s05-s02);
    float k0 = s10 + tx*(s13-s10);
    float k1 = s11 + tx*(s14-s11);
    float k2 = s12 + tx*(s15-s12);
    float o0 = h0 + ty*(k0-h0);
    float o1 = h1 + ty*(k1-h1);
    float o2 = h2 + ty*(k2-h2);
    float cl = (fabsf(o0-c0)+fabsf(o1-c1)+fabsf(o2-c2)) * (1.0f/3.0f);

    clbuf[(size_t)nb*RWH + pix] = cl;    // == clbuf[n*NPIX + (b*RWH+pix)]

    // grad loss on the center-view blocks (u=3,v=3): same math as fused
    if (n == 24) {
        float lx = 0.0f, ly = 0.0f;
        if (xx <= 246) {
            f2u q1 = *(const f2u*)(cbase + 4);
            float wx = __expf(-50.0f * (fabsf(cv.w-c0) + fabsf(q1.x-c1) + fabsf(q1.y-c2)));
            lx = wx * fabsf(pred[pidx + 1] - p);
        }
        if (yy <= 246) {
            f4u r = *(const f4u*)(cbase + ROWF);
            float wy = __expf(-50.0f * (fabsf(r.x-c0) + fabsf(r.y-c1) + fabsf(r.z-c2)));
            ly = wy * fabsf(pred[pidx + Wimg] - p);
        }
        #pragma unroll
        for (int off = 32; off > 0; off >>= 1) {
            lx += __shfl_down(lx, off);
            ly += __shfl_down(ly, off);
        }
        if ((tid & 63) == 0) {
            atomicAdd(acc + 1, (double)lx);
            atomicAdd(acc + 2, (double)ly);
        }
    }
}

// ===========================================================================
// Kernel B: one lane = one pixel. Reads its 49 cl (coalesced, stride NPIX),
// gauss + all-pairs stable rank + tail sum entirely in registers. Tie-break
// uses compile-time (m<n): cnt += (m<n) ? (bm>=bn) : (bm>bn) -- identical
// order to the packed (bits<<8)|(255-idx) u64 keys, 1 cmp/pair.
// ===========================================================================

__global__ __launch_bounds__(256) void rank_kernel(
    const float* __restrict__ clbuf, const float* __restrict__ y,
    const int* __restrict__ epoch_p, double* __restrict__ acc)
{
    __shared__ float sred[4];
    const int tid  = threadIdx.x;
    int gpix = blockIdx.x*256 + tid;     // 0..230399 ; block is batch-uniform
    int b    = gpix / RWH;
    int pix  = gpix - b*RWH;
    int ry   = pix / RW, rx = pix - ry*RW;
    int yy   = 8 + ry,   xx = 8 + rx;
    float yval = y[(b*Himg + yy)*Wimg + xx];
    const int epoch = *epoch_p;

    float cl[49];
    #pragma unroll
    for (int n = 0; n < 49; n++)
        cl[n] = clbuf[(size_t)n*NPIX + gpix];

    // angular gaussian (edge-replicated), exact tap order as reference
    float g[49];
    if (epoch > 0) {
        #pragma unroll
        for (int u = 0; u < 7; u++) {
            const int um1 = (u > 0) ? u-1 : 0;
            const int up1 = (u < 6) ? u+1 : 6;
            #pragma unroll
            for (int v = 0; v < 7; v++) {
                const int vm = (v > 0) ? v-1 : 0;
                const int vp = (v < 6) ? v+1 : 6;
                g[u*7+v] =
                    0.0751f*cl[um1*7+vm] + 0.1238f*cl[um1*7+v] + 0.0751f*cl[um1*7+vp] +
                    0.1238f*cl[u*7+vm]   + 0.2042f*cl[u*7+v]   + 0.1238f*cl[u*7+vp] +
                    0.0751f*cl[up1*7+vm] + 0.1238f*cl[up1*7+v] + 0.0751f*cl[up1*7+vp];
            }
        }
    } else {
        #pragma unroll
        for (int n = 0; n < 49; n++) g[n] = cl[n];
    }

    // stable-descending rank; keys >= 0 so u32 bits order == float order
    float tail = 0.0f;
    #pragma unroll
    for (int n = 0; n < 49; n++) {
        unsigned int bn = __float_as_uint(g[n]);
        int cnt = 0;
        #pragma unroll
        for (int m = 0; m < 49; m++) {
            if (m == n) continue;
            unsigned int bm = __float_as_uint(g[m]);
            cnt += ((m < n) ? (bm >= bn) : (bm > bn)) ? 1 : 0;
        }
        tail += ((float)cnt > yval) ? cl[n] : 0.0f;
    }
    float contrib = tail * (49.0f / (49.0f - yval));

    #pragma unroll
    for (int off = 32; off > 0; off >>= 1)
        contrib += __shfl_down(contrib, off);
    if ((tid & 63) == 0) sred[tid >> 6] = contrib;
    __syncthreads();
    if (tid == 0)
        atomicAdd(acc + 0, (double)(sred[0] + sred[1] + sred[2] + sred[3]));
}

// ===========================================================================
// FUSED FALLBACK (R3 kernel, proven pass) -- used only if ws_size too small
// ===========================================================================

__global__ __launch_bounds__(448, 4) void color_kernel(
    const float* __restrict__ pred, const float* __restrict__ x,
    const float* __restrict__ y, const int* __restrict__ epoch_p,
    double* __restrict__ acc)
{
    __shared__ float s_cl[64 * NVP];
    __shared__ float s_g [64 * NVP];
    __shared__ float sred[8];

    const int tid = threadIdx.x;
    const int pix = tid & 63;
    const int sub = __builtin_amdgcn_readfirstlane(tid >> 6);   // 0..6

    int lb  = (blockIdx.x & 7) * (NBLK/8) + (blockIdx.x >> 3);
    int pid = lb * 64 + pix;
    int b   = pid / RWH;
    int rem = pid - b * RWH;
    int ry  = rem / RW;
    int yy  = 8 + ry;
    int xx  = 8 + (rem - ry * RW);

    int pidx = (b * Himg + yy) * Wimg + xx;
    float p    = pred[pidx];
    float yval = y[pidx];
    const int epoch = *epoch_p;

    const float* xv    = x + (size_t)b * (49 * IMGF);
    const float* cbase = xv + (24 * IMGF) + (yy * Wimg + xx) * 3;
    f4u cv = *(const f4u*)cbase;
    float c0 = cv.x, c1 = cv.y, c2 = cv.z;

    float* mycl = s_cl + pix * NVP;
    float* myg  = s_g  + pix * NVP;

    int co[7]; float txv[7];
    #pragma unroll
    for (int vv = 0; vv < 7; vv++) {
        float cx = fminf(fmaxf((float)xx + p * (float)(vv-3), 0.0f), 255.0f);
        float x0f = floorf(cx);
        float tx = cx - x0f;
        int ix0 = (int)x0f;
        if (ix0 >= 255) { ix0 = 254; tx = 1.0f; }
        co[vv] = ix0 * 3; txv[vv] = tx;
    }

    float creg[7];
    {
        float cy = fminf(fmaxf((float)yy + p * (float)(sub-3), 0.0f), 255.0f);
        float y0f = floorf(cy);
        float ty = cy - y0f;
        int iy0 = (int)y0f;
        int iy1 = min(iy0+1, 255);
        int ro0 = iy0*ROWF, ro1 = iy1*ROWF;
        const float* vbase = xv + sub * 7 * IMGF;

        f4u a0[4], b0[4]; f2u a1[4], b1[4];

#define LOADV(VV, S) { \
        const float* s0p = vbase + (VV)*IMGF + ro0 + co[VV]; \
        const float* s1p = vbase + (VV)*IMGF + ro1 + co[VV]; \
        a0[S] = *(const f4u*)s0p;  a1[S] = *(const f2u*)(s0p + 4); \
        b0[S] = *(const f4u*)s1p;  b1[S] = *(const f2u*)(s1p + 4); }

        LOADV(0,0) LOADV(1,1) LOADV(2,2)
        __builtin_amdgcn_sched_barrier(0);

        #pragma unroll
        for (int vv = 0; vv < 7; vv++) {
            if (vv + 3 < 7) { LOADV(vv+3, (vv+3)&3) }
            __builtin_amdgcn_sched_barrier(0);
            const int S = vv & 3;
            float tx = txv[vv];
            float s00 = a0[S].x, s01 = a0[S].y, s02 = a0[S].z;
            float s03 = a0[S].w, s04 = a1[S].x, s05 = a1[S].y;
            float s10 = b0[S].x, s11 = b0[S].y, s12 = b0[S].z;
            float s13 = b0[S].w, s14 = b1[S].x, s15 = b1[S].y;
            float h0 = s00 + tx*(s03-s00);
            float h1 = s01 + tx*(s04-s01);
            float h2 = s02 + tx*(s05-s02);
            float k0 = s10 + tx*(s13-s10);
            float k1 = s11 + tx*(s14-s11);
            float k2 = s12 + tx*(s15-s12);
            float o0 = h0 + ty*(k0-h0);
            float o1 = h1 + ty*(k1-h1);
            float o2 = h2 + ty*(k2-h2);
            float cl = (fabsf(o0-c0)+fabsf(o1-c1)+fabsf(o2-c2)) * (1.0f/3.0f);
            creg[vv] = cl;
            mycl[sub*7 + vv] = cl;
            __builtin_amdgcn_sched_barrier(0);
        }
#undef LOADV
    }

    if (sub == 3) {
        float lx = 0.0f, ly = 0.0f;
        if (xx <= 246) {
            f4u q0 = *(const f4u*)cbase;
            f2u q1 = *(const f2u*)(cbase + 4);
            float wx = __expf(-50.0f * (fabsf(q0.w-c0) + fabsf(q1.x-c1) + fabsf(q1.y-c2)));
            lx = wx * fabsf(pred[pidx + 1] - p);
        }
        if (yy <= 246) {
            f4u r = *(const f4u*)(cbase + ROWF);
            float wy = __expf(-50.0f * (fabsf(r.x-c0) + fabsf(r.y-c1) + fabsf(r.z-c2)));
            ly = wy * fabsf(pred[pidx + Wimg] - p);
        }
        #pragma unroll
        for (int off = 32; off > 0; off >>= 1) {
            lx += __shfl_down(lx, off);
            ly += __shfl_down(ly, off);
        }
        if (pix == 0) {
            atomicAdd(acc + 1, (double)lx);
            atomicAdd(acc + 2, (double)ly);
        }
    }
    __syncthreads();

    if (epoch > 0) {
        const int um1 = (sub > 0) ? sub-1 : 0;
        const int up1 = (sub < 6) ? sub+1 : 6;
        const float* rm = mycl + um1*7;
        const float* rc = mycl + sub*7;
        const float* rp = mycl + up1*7;
        #pragma unroll
        for (int vv = 0; vv < 7; vv++) {
            const int vm = (vv > 0) ? vv-1 : 0;
            const int vp = (vv < 6) ? vv+1 : 6;
            myg[sub*7 + vv] =
                0.0751f*rm[vm] + 0.1238f*rm[vv] + 0.0751f*rm[vp] +
                0.1238f*rc[vm] + 0.2042f*rc[vv] + 0.1238f*rc[vp] +
                0.0751f*rp[vm] + 0.1238f*rp[vv] + 0.0751f*rp[vp];
        }
    }
    __syncthreads();

    const float* keyb = (epoch > 0) ? myg : mycl;

    f4a kv[13];
    #pragma unroll
    for (int i = 0; i < 13; i++)
        kv[i] = *(const f4a*)(keyb + 4*i);

    unsigned long long kn[7];
    int cnt[7];
    #pragma unroll
    for (int i = 0; i < 7; i++) {
        int n = sub*7 + i;
        unsigned int bb = __float_as_uint(keyb[n]);
        kn[i] = (((unsigned long long)bb) << 8) | (unsigned long long)(255 - n);
        cnt[i] = 0;
    }
    #pragma unroll
    for (int m = 0; m < NV; m++) {
        unsigned int bm = __float_as_uint(kv[m>>2][m&3]);
        unsigned long long km = (((unsigned long long)bm) << 8) | (unsigned long long)(255 - m);
        #pragma unroll
        for (int i = 0; i < 7; i++)
            cnt[i] += (km > kn[i]) ? 1 : 0;
    }
    float tail = 0.0f;
    #pragma unroll
    for (int i = 0; i < 7; i++)
        tail += ((float)cnt[i] > yval) ? creg[i] : 0.0f;
    float contrib = tail * (49.0f / (49.0f - yval));

    #pragma unroll
    for (int off = 32; off > 0; off >>= 1)
        contrib += __shfl_down(contrib, off);
    if (pix == 0) sred[sub] = contrib;
    __syncthreads();
    if (tid == 0) {
        double s = 0.0;
        #pragma unroll
        for (int i = 0; i < 7; i++) s += (double)sred[i];
        atomicAdd(acc + 0, s);
    }
}

__global__ void finalize_kernel(const double* __restrict__ acc,
                                float* __restrict__ out)
{
    double cl = acc[0] / 11289600.0;           // 4*49*240*240
    double gl = (acc[1] + acc[2]) / (2.0 * 229440.0);  // 4*240*239 each
    out[0] = (float)(cl + 0.1 * gl);
}

extern "C" void kernel_launch(void* const* d_in, const int* in_sizes, int n_in,
                              void* d_out, int out_size, void* d_ws, size_t ws_size,
                              hipStream_t stream)
{
    const float* pred  = (const float*)d_in[0];
    const float* x     = (const float*)d_in[1];
    const float* y     = (const float*)d_in[2];
    const int*   epoch = (const int*)d_in[3];
    double* acc  = (double*)d_ws;

    hipMemsetAsync(acc, 0, 3 * sizeof(double), stream);

    const size_t need = 256 + (size_t)NV * NPIX * sizeof(float);   // ~45.2 MB
    if (ws_size >= need) {
        float* clbuf = (float*)((char*)d_ws + 256);
        dim3 ga(RWH/256, 196);   // (225, 49 views * 4 batches)
        cl_kernel<<<ga, 256, 0, stream>>>(pred, x, clbuf, acc);
        rank_kernel<<<NPIX/256, 256, 0, stream>>>(clbuf, y, epoch, acc);
    } else {
        color_kernel<<<NBLK, 448, 0, stream>>>(pred, x, y, epoch, acc);
    }
    finalize_kernel<<<1, 1, 0, stream>>>(acc, (float*)d_out);
}

// Round 6
// 439.627 us; speedup vs baseline: 1.1325x; 1.1325x over previous
//
#include <hip/hip_runtime.h>
#include <math.h>

#define NV    49
#define NVP   52
#define Himg  256
#define Wimg  256
#define RW    240
#define RWH   (RW*RW)          // 57600
#define NPIX  (4*RWH)          // 230400
#define ROWF  (Wimg*3)         // 768 floats per image row
#define IMGF  (Himg*Wimg*3)    // 196608 floats per view image
#define NBLK  (NPIX/64)        // 3600 blocks (fused fallback)
#define CHNK  (RWH/256)        // 225 pixel-chunks per (b,view) image
#define TBLK  (CHNK*196)       // 44100 total blocks in split gather

// 4B-aligned wide vector loads (gfx950 global loads legal at dword align)
typedef float f4u __attribute__((ext_vector_type(4), aligned(4)));
typedef float f2u __attribute__((ext_vector_type(2), aligned(4)));
typedef float f4a __attribute__((ext_vector_type(4), aligned(16)));

// ===========================================================================
// SPLIT PATH -- R5 proved the split decouples the VALU phase (occupancy 85%)
// but lost XCD locality: FETCH 498 MB vs fused 78 MB (same reads, 6.4x).
// The gather scatters +/-9 rows per lane (p ~ N(0,1)); adjacent pixel-chunks
// share most row-lines. R5's 2D grid round-robined adjacent chunks across 8
// non-coherent L2s -> 8x re-fetch + L3 thrash.
// Fix: 1D grid, bijective XCD band mapping (44100 = 8*5512+4): XCD k streams
// a contiguous run of (batch-major image, chunk) work, so row-overlap and
// the per-batch center/pred reuse stay in ONE 4 MB L2 (~2-3 MB working set).
// ===========================================================================

__global__ __launch_bounds__(256) void cl_kernel(
    const float* __restrict__ pred, const float* __restrict__ x,
    float* __restrict__ clbuf, double* __restrict__ acc)
{
    const int tid = threadIdx.x;

    // --- bijective XCD band swizzle (m204 formula) ---
    // dispatch round-robins linear id across XCDs: xcd = lin & 7
    // XCDs 0..3 own 5513 blocks, 4..7 own 5512; band_start = xcd*5512+min(xcd,4)
    int lin  = blockIdx.x;               // 0..44099
    int xcd  = lin & 7;
    int ord  = lin >> 3;
    int myblk = xcd*5512 + ((xcd < 4) ? xcd : 4) + ord;

    // batch-major decode: each band streams one batch's images consecutively
    int q     = myblk / CHNK;            // 0..195
    int chunk = myblk - q*CHNK;          // 0..224
    int b     = q / NV;                  // 0..3
    int n     = q - b*NV;                // 0..48
    int u     = n / 7, v = n - u*7;

    int pix = chunk*256 + tid;           // 0..57599 within (b, view)
    int ry  = pix / RW;
    int rx  = pix - ry*RW;
    int yy  = 8 + ry, xx = 8 + rx;
    int pidx = (b*Himg + yy)*Wimg + xx;
    float p = pred[pidx];

    const float* xv    = x + (size_t)b * (49*IMGF);
    const float* cbase = xv + 24*IMGF + (yy*Wimg+xx)*3;
    f4u cv = *(const f4u*)cbase;         // center texel (always in-bounds)
    float c0 = cv.x, c1 = cv.y, c2 = cv.z;

    // x interpolant for this view's v
    float cx  = fminf(fmaxf((float)xx + p*(float)(v-3), 0.0f), 255.0f);
    float x0f = floorf(cx);
    float tx  = cx - x0f;
    int ix0   = (int)x0f;
    if (ix0 >= 255) { ix0 = 254; tx = 1.0f; }   // same bilinear result
    // y interpolant for this view's u
    float cy  = fminf(fmaxf((float)yy + p*(float)(u-3), 0.0f), 255.0f);
    float y0f = floorf(cy);
    float ty  = cy - y0f;
    int iy0   = (int)y0f;
    int iy1   = min(iy0+1, 255);

    const float* ib  = xv + n*IMGF;
    const float* s0p = ib + iy0*ROWF + ix0*3;
    const float* s1p = ib + iy1*ROWF + ix0*3;
    f4u a0 = *(const f4u*)s0p;  f2u a1 = *(const f2u*)(s0p + 4);
    f4u b0 = *(const f4u*)s1p;  f2u b1 = *(const f2u*)(s1p + 4);

    float s00 = a0.x, s01 = a0.y, s02 = a0.z;
    float s03 = a0.w, s04 = a1.x, s05 = a1.y;
    float s10 = b0.x, s11 = b0.y, s12 = b0.z;
    float s13 = b0.w, s14 = b1.x, s15 = b1.y;
    float h0 = s00 + tx*(s03-s00);
    float h1 = s01 + tx*(s04-s01);
    float h2 = s02 + tx*(s05-s02);
    float k0 = s10 + tx*(s13-s10);
    float k1 = s11 + tx*(s14-s11);
    float k2 = s12 + tx*(s15-s12);
    float o0 = h0 + ty*(k0-h0);
    float o1 = h1 + ty*(k1-h1);
    float o2 = h2 + ty*(k2-h2);
    float cl = (fabsf(o0-c0)+fabsf(o1-c1)+fabsf(o2-c2)) * (1.0f/3.0f);

    clbuf[(size_t)n*NPIX + b*RWH + pix] = cl;

    // grad loss on the center-view blocks (u=3,v=3): same math as fused
    if (n == 24) {
        float lx = 0.0f, ly = 0.0f;
        if (xx <= 246) {
            f2u q1 = *(const f2u*)(cbase + 4);
            float wx = __expf(-50.0f * (fabsf(cv.w-c0) + fabsf(q1.x-c1) + fabsf(q1.y-c2)));
            lx = wx * fabsf(pred[pidx + 1] - p);
        }
        if (yy <= 246) {
            f4u r = *(const f4u*)(cbase + ROWF);
            float wy = __expf(-50.0f * (fabsf(r.x-c0) + fabsf(r.y-c1) + fabsf(r.z-c2)));
            ly = wy * fabsf(pred[pidx + Wimg] - p);
        }
        #pragma unroll
        for (int off = 32; off > 0; off >>= 1) {
            lx += __shfl_down(lx, off);
            ly += __shfl_down(ly, off);
        }
        if ((tid & 63) == 0) {
            atomicAdd(acc + 1, (double)lx);
            atomicAdd(acc + 2, (double)ly);
        }
    }
}

// ===========================================================================
// Kernel B: one lane = one pixel. Reads its 49 cl (coalesced, stride NPIX),
// gauss + all-pairs stable rank + tail sum entirely in registers. Tie-break
// uses compile-time (m<n): cnt += (m<n) ? (bm>=bn) : (bm>bn) -- identical
// order to the packed (bits<<8)|(255-idx) u64 keys, 1 cmp/pair.
// ===========================================================================

__global__ __launch_bounds__(256) void rank_kernel(
    const float* __restrict__ clbuf, const float* __restrict__ y,
    const int* __restrict__ epoch_p, double* __restrict__ acc)
{
    __shared__ float sred[4];
    const int tid  = threadIdx.x;
    int gpix = blockIdx.x*256 + tid;     // 0..230399 ; block is batch-uniform
    int b    = gpix / RWH;
    int pix  = gpix - b*RWH;
    int ry   = pix / RW, rx = pix - ry*RW;
    int yy   = 8 + ry,   xx = 8 + rx;
    float yval = y[(b*Himg + yy)*Wimg + xx];
    const int epoch = *epoch_p;

    float cl[49];
    #pragma unroll
    for (int n = 0; n < 49; n++)
        cl[n] = clbuf[(size_t)n*NPIX + gpix];

    // angular gaussian (edge-replicated), exact tap order as reference
    float g[49];
    if (epoch > 0) {
        #pragma unroll
        for (int u = 0; u < 7; u++) {
            const int um1 = (u > 0) ? u-1 : 0;
            const int up1 = (u < 6) ? u+1 : 6;
            #pragma unroll
            for (int v = 0; v < 7; v++) {
                const int vm = (v > 0) ? v-1 : 0;
                const int vp = (v < 6) ? v+1 : 6;
                g[u*7+v] =
                    0.0751f*cl[um1*7+vm] + 0.1238f*cl[um1*7+v] + 0.0751f*cl[um1*7+vp] +
                    0.1238f*cl[u*7+vm]   + 0.2042f*cl[u*7+v]   + 0.1238f*cl[u*7+vp] +
                    0.0751f*cl[up1*7+vm] + 0.1238f*cl[up1*7+v] + 0.0751f*cl[up1*7+vp];
            }
        }
    } else {
        #pragma unroll
        for (int n = 0; n < 49; n++) g[n] = cl[n];
    }

    // stable-descending rank; keys >= 0 so u32 bits order == float order
    float tail = 0.0f;
    #pragma unroll
    for (int n = 0; n < 49; n++) {
        unsigned int bn = __float_as_uint(g[n]);
        int cnt = 0;
        #pragma unroll
        for (int m = 0; m < 49; m++) {
            if (m == n) continue;
            unsigned int bm = __float_as_uint(g[m]);
            cnt += ((m < n) ? (bm >= bn) : (bm > bn)) ? 1 : 0;
        }
        tail += ((float)cnt > yval) ? cl[n] : 0.0f;
    }
    float contrib = tail * (49.0f / (49.0f - yval));

    #pragma unroll
    for (int off = 32; off > 0; off >>= 1)
        contrib += __shfl_down(contrib, off);
    if ((tid & 63) == 0) sred[tid >> 6] = contrib;
    __syncthreads();
    if (tid == 0)
        atomicAdd(acc + 0, (double)(sred[0] + sred[1] + sred[2] + sred[3]));
}

// ===========================================================================
// FUSED FALLBACK (R3 kernel, proven pass) -- used only if ws_size too small
// ===========================================================================

__global__ __launch_bounds__(448, 4) void color_kernel(
    const float* __restrict__ pred, const float* __restrict__ x,
    const float* __restrict__ y, const int* __restrict__ epoch_p,
    double* __restrict__ acc)
{
    __shared__ float s_cl[64 * NVP];
    __shared__ float s_g [64 * NVP];
    __shared__ float sred[8];

    const int tid = threadIdx.x;
    const int pix = tid & 63;
    const int sub = __builtin_amdgcn_readfirstlane(tid >> 6);   // 0..6

    int lb  = (blockIdx.x & 7) * (NBLK/8) + (blockIdx.x >> 3);
    int pid = lb * 64 + pix;
    int b   = pid / RWH;
    int rem = pid - b * RWH;
    int ry  = rem / RW;
    int yy  = 8 + ry;
    int xx  = 8 + (rem - ry * RW);

    int pidx = (b * Himg + yy) * Wimg + xx;
    float p    = pred[pidx];
    float yval = y[pidx];
    const int epoch = *epoch_p;

    const float* xv    = x + (size_t)b * (49 * IMGF);
    const float* cbase = xv + (24 * IMGF) + (yy * Wimg + xx) * 3;
    f4u cv = *(const f4u*)cbase;
    float c0 = cv.x, c1 = cv.y, c2 = cv.z;

    float* mycl = s_cl + pix * NVP;
    float* myg  = s_g  + pix * NVP;

    int co[7]; float txv[7];
    #pragma unroll
    for (int vv = 0; vv < 7; vv++) {
        float cx = fminf(fmaxf((float)xx + p * (float)(vv-3), 0.0f), 255.0f);
        float x0f = floorf(cx);
        float tx = cx - x0f;
        int ix0 = (int)x0f;
        if (ix0 >= 255) { ix0 = 254; tx = 1.0f; }
        co[vv] = ix0 * 3; txv[vv] = tx;
    }

    float creg[7];
    {
        float cy = fminf(fmaxf((float)yy + p * (float)(sub-3), 0.0f), 255.0f);
        float y0f = floorf(cy);
        float ty = cy - y0f;
        int iy0 = (int)y0f;
        int iy1 = min(iy0+1, 255);
        int ro0 = iy0*ROWF, ro1 = iy1*ROWF;
        const float* vbase = xv + sub * 7 * IMGF;

        f4u a0[4], b0[4]; f2u a1[4], b1[4];

#define LOADV(VV, S) { \
        const float* s0p = vbase + (VV)*IMGF + ro0 + co[VV]; \
        const float* s1p = vbase + (VV)*IMGF + ro1 + co[VV]; \
        a0[S] = *(const f4u*)s0p;  a1[S] = *(const f2u*)(s0p + 4); \
        b0[S] = *(const f4u*)s1p;  b1[S] = *(const f2u*)(s1p + 4); }

        LOADV(0,0) LOADV(1,1) LOADV(2,2)
        __builtin_amdgcn_sched_barrier(0);

        #pragma unroll
        for (int vv = 0; vv < 7; vv++) {
            if (vv + 3 < 7) { LOADV(vv+3, (vv+3)&3) }
            __builtin_amdgcn_sched_barrier(0);
            const int S = vv & 3;
            float tx = txv[vv];
            float s00 = a0[S].x, s01 = a0[S].y, s02 = a0[S].z;
            float s03 = a0[S].w, s04 = a1[S].x, s05 = a1[S].y;
            float s10 = b0[S].x, s11 = b0[S].y, s12 = b0[S].z;
            float s13 = b0[S].w, s14 = b1[S].x, s15 = b1[S].y;
            float h0 = s00 + tx*(s03-s00);
            float h1 = s01 + tx*(s04-s01);
            float h2 = s02 + tx*(s05-s02);
            float k0 = s10 + tx*(s13-s10);
            float k1 = s11 + tx*(s14-s11);
            float k2 = s12 + tx*(s15-s12);
            float o0 = h0 + ty*(k0-h0);
            float o1 = h1 + ty*(k1-h1);
            float o2 = h2 + ty*(k2-h2);
            float cl = (fabsf(o0-c0)+fabsf(o1-c1)+fabsf(o2-c2)) * (1.0f/3.0f);
            creg[vv] = cl;
            mycl[sub*7 + vv] = cl;
            __builtin_amdgcn_sched_barrier(0);
        }
#undef LOADV
    }

    if (sub == 3) {
        float lx = 0.0f, ly = 0.0f;
        if (xx <= 246) {
            f4u q0 = *(const f4u*)cbase;
            f2u q1 = *(const f2u*)(cbase + 4);
            float wx = __expf(-50.0f * (fabsf(q0.w-c0) + fabsf(q1.x-c1) + fabsf(q1.y-c2)));
            lx = wx * fabsf(pred[pidx + 1] - p);
        }
        if (yy <= 246) {
            f4u r = *(const f4u*)(cbase + ROWF);
            float wy = __expf(-50.0f * (fabsf(r.x-c0) + fabsf(r.y-c1) + fabsf(r.z-c2)));
            ly = wy * fabsf(pred[pidx + Wimg] - p);
        }
        #pragma unroll
        for (int off = 32; off > 0; off >>= 1) {
            lx += __shfl_down(lx, off);
            ly += __shfl_down(ly, off);
        }
        if (pix == 0) {
            atomicAdd(acc + 1, (double)lx);
            atomicAdd(acc + 2, (double)ly);
        }
    }
    __syncthreads();

    if (epoch > 0) {
        const int um1 = (sub > 0) ? sub-1 : 0;
        const int up1 = (sub < 6) ? sub+1 : 6;
        const float* rm = mycl + um1*7;
        const float* rc = mycl + sub*7;
        const float* rp = mycl + up1*7;
        #pragma unroll
        for (int vv = 0; vv < 7; vv++) {
            const int vm = (vv > 0) ? vv-1 : 0;
            const int vp = (vv < 6) ? vv+1 : 6;
            myg[sub*7 + vv] =
                0.0751f*rm[vm] + 0.1238f*rm[vv] + 0.0751f*rm[vp] +
                0.1238f*rc[vm] + 0.2042f*rc[vv] + 0.1238f*rc[vp] +
                0.0751f*rp[vm] + 0.1238f*rp[vv] + 0.0751f*rp[vp];
        }
    }
    __syncthreads();

    const float* keyb = (epoch > 0) ? myg : mycl;

    f4a kv[13];
    #pragma unroll
    for (int i = 0; i < 13; i++)
        kv[i] = *(const f4a*)(keyb + 4*i);

    unsigned long long kn[7];
    int cnt[7];
    #pragma unroll
    for (int i = 0; i < 7; i++) {
        int n = sub*7 + i;
        unsigned int bb = __float_as_uint(keyb[n]);
        kn[i] = (((unsigned long long)bb) << 8) | (unsigned long long)(255 - n);
        cnt[i] = 0;
    }
    #pragma unroll
    for (int m = 0; m < NV; m++) {
        unsigned int bm = __float_as_uint(kv[m>>2][m&3]);
        unsigned long long km = (((unsigned long long)bm) << 8) | (unsigned long long)(255 - m);
        #pragma unroll
        for (int i = 0; i < 7; i++)
            cnt[i] += (km > kn[i]) ? 1 : 0;
    }
    float tail = 0.0f;
    #pragma unroll
    for (int i = 0; i < 7; i++)
        tail += ((float)cnt[i] > yval) ? creg[i] : 0.0f;
    float contrib = tail * (49.0f / (49.0f - yval));

    #pragma unroll
    for (int off = 32; off > 0; off >>= 1)
        contrib += __shfl_down(contrib, off);
    if (pix == 0) sred[sub] = contrib;
    __syncthreads();
    if (tid == 0) {
        double s = 0.0;
        #pragma unroll
        for (int i = 0; i < 7; i++) s += (double)sred[i];
        atomicAdd(acc + 0, s);
    }
}

__global__ void finalize_kernel(const double* __restrict__ acc,
                                float* __restrict__ out)
{
    double cl = acc[0] / 11289600.0;           // 4*49*240*240
    double gl = (acc[1] + acc[2]) / (2.0 * 229440.0);  // 4*240*239 each
    out[0] = (float)(cl + 0.1 * gl);
}

extern "C" void kernel_launch(void* const* d_in, const int* in_sizes, int n_in,
                              void* d_out, int out_size, void* d_ws, size_t ws_size,
                              hipStream_t stream)
{
    const float* pred  = (const float*)d_in[0];
    const float* x     = (const float*)d_in[1];
    const float* y     = (const float*)d_in[2];
    const int*   epoch = (const int*)d_in[3];
    double* acc  = (double*)d_ws;

    hipMemsetAsync(acc, 0, 3 * sizeof(double), stream);

    const size_t need = 256 + (size_t)NV * NPIX * sizeof(float);   // ~45.2 MB
    if (ws_size >= need) {
        float* clbuf = (float*)((char*)d_ws + 256);
        cl_kernel<<<TBLK, 256, 0, stream>>>(pred, x, clbuf, acc);
        rank_kernel<<<NPIX/256, 256, 0, stream>>>(clbuf, y, epoch, acc);
    } else {
        color_kernel<<<NBLK, 448, 0, stream>>>(pred, x, y, epoch, acc);
    }
    finalize_kernel<<<1, 1, 0, stream>>>(acc, (float*)d_out);
}

// Round 7
// 420.101 us; speedup vs baseline: 1.1851x; 1.0465x over previous
//
#include <hip/hip_runtime.h>
#include <math.h>

#define NV    49
#define NVP   52
#define Himg  256
#define Wimg  256
#define RW    240
#define RWH   (RW*RW)          // 57600
#define NPIX  (4*RWH)          // 230400
#define ROWF  (Wimg*3)         // 768 floats per image row
#define IMGF  (Himg*Wimg*3)    // 196608 floats per view image
#define NBLK  (NPIX/64)        // 3600 blocks (fused fallback)

// staged-gather geometry
#define HS    8                // output rows per strip
#define NSTRP (RW/HS)          // 30 strips per (b,view)
#define TBLKS (NSTRP*196)      // 5880 blocks (divisible by 8: 735/XCD)
#define RSTG  22               // staged source rows: [Y-7, Y+14]
#define LDSW  772              // padded LDS row stride in floats (768+4)

// 4B-aligned wide vector loads (gfx950 global loads legal at dword align)
typedef float f4u __attribute__((ext_vector_type(4), aligned(4)));
typedef float f2u __attribute__((ext_vector_type(2), aligned(4)));
typedef float f4a __attribute__((ext_vector_type(4), aligned(16)));

// ===========================================================================
// Kernel A (staged): R5/R6 localized the wall to vector-memory TRANSACTIONS:
// row-scattered gathers (p ~ N(0,1), +/-9 rows/lane) decompose each load into
// ~40-60 cache-line txns; ~33M txns / 256 CUs ~= 155us in BOTH the fused and
// split structures (HBM 9%, VALU 12% -> neither is the limit).
// Fix: stage 22 full-width image rows per block in LDS (coalesced float4),
// gather bilinear taps from LDS (DS pipe, no TA txns). Lanes outside the
// +/-7-row window (~1.4%) take the original global path (exec-masked).
// ===========================================================================

__global__ __launch_bounds__(256, 2) void cl_kernel(
    const float* __restrict__ pred, const float* __restrict__ x,
    float* __restrict__ clbuf, double* __restrict__ acc)
{
    __shared__ float tile[RSTG * LDSW];      // 67,936 B -> 2 blocks/CU

    const int tid = threadIdx.x;

    // bijective XCD band swizzle: 5880 = 8 * 735
    int myblk = (blockIdx.x & 7) * 735 + (blockIdx.x >> 3);
    int q     = myblk / NSTRP;               // 0..195  (b*49 + n)
    int s     = myblk - q * NSTRP;           // 0..29
    int b     = q / NV;
    int n     = q - b * NV;
    int u     = n / 7, v = n - u * 7;
    int Y     = 8 + s * HS;                  // first output row, 8..240
    int r0    = Y - 7;                       // staged rows r0..r0+21 (1..254)

    const float* xv = x + (size_t)b * (49 * IMGF);
    const float* ib = xv + n * IMGF;

    // ---- stage 22 source rows (full width) into LDS, coalesced ----
    {
        const float* src = ib + r0 * ROWF;
        for (int j = tid; j < RSTG * (ROWF/4); j += 256) {   // 4224 f4 chunks
            int r  = j / (ROWF/4);
            int c4 = j - r * (ROWF/4);
            f4a val = *(const f4a*)(src + j * 4);
            *(f4a*)&tile[r * LDSW + c4 * 4] = val;
        }
    }
    __syncthreads();

    // ---- compute 8x240 output pixels, 7.5 px/thread ----
    float lx_acc = 0.0f, ly_acc = 0.0f;

    for (int i = tid; i < HS * RW; i += 256) {
        int py = i / RW;
        int px = i - py * RW;
        int yy = Y + py;
        int xx = 8 + px;
        int pidx = (b * Himg + yy) * Wimg + xx;
        float p = pred[pidx];

        const float* cbase = xv + 24 * IMGF + (yy * Wimg + xx) * 3;
        f4u cv = *(const f4u*)cbase;         // center texel (in-bounds)
        float c0 = cv.x, c1 = cv.y, c2 = cv.z;

        // x interpolant
        float cx  = fminf(fmaxf((float)xx + p * (float)(v - 3), 0.0f), 255.0f);
        float x0f = floorf(cx);
        float tx  = cx - x0f;
        int ix0   = (int)x0f;
        if (ix0 >= 255) { ix0 = 254; tx = 1.0f; }
        // y interpolant
        float cy  = fminf(fmaxf((float)yy + p * (float)(u - 3), 0.0f), 255.0f);
        float y0f = floorf(cy);
        float ty  = cy - y0f;
        int iy0   = (int)y0f;
        int iy1   = min(iy0 + 1, 255);

        float s00, s01, s02, s03, s04, s05;
        float s10, s11, s12, s13, s14, s15;

        bool ok = (iy0 >= r0) && (iy1 <= r0 + RSTG - 1);
        if (ok) {
            int b0 = (iy0 - r0) * LDSW + ix0 * 3;
            int b1 = (iy1 - r0) * LDSW + ix0 * 3;
            s00 = tile[b0+0]; s01 = tile[b0+1]; s02 = tile[b0+2];
            s03 = tile[b0+3]; s04 = tile[b0+4]; s05 = tile[b0+5];
            s10 = tile[b1+0]; s11 = tile[b1+1]; s12 = tile[b1+2];
            s13 = tile[b1+3]; s14 = tile[b1+4]; s15 = tile[b1+5];
        } else {
            const float* s0p = ib + iy0 * ROWF + ix0 * 3;
            const float* s1p = ib + iy1 * ROWF + ix0 * 3;
            f4u a0 = *(const f4u*)s0p;  f2u a1 = *(const f2u*)(s0p + 4);
            f4u b0 = *(const f4u*)s1p;  f2u b1 = *(const f2u*)(s1p + 4);
            s00 = a0.x; s01 = a0.y; s02 = a0.z; s03 = a0.w; s04 = a1.x; s05 = a1.y;
            s10 = b0.x; s11 = b0.y; s12 = b0.z; s13 = b0.w; s14 = b1.x; s15 = b1.y;
        }

        float h0 = s00 + tx*(s03-s00);
        float h1 = s01 + tx*(s04-s01);
        float h2 = s02 + tx*(s05-s02);
        float k0 = s10 + tx*(s13-s10);
        float k1 = s11 + tx*(s14-s11);
        float k2 = s12 + tx*(s15-s12);
        float o0 = h0 + ty*(k0-h0);
        float o1 = h1 + ty*(k1-h1);
        float o2 = h2 + ty*(k2-h2);
        float cl = (fabsf(o0-c0)+fabsf(o1-c1)+fabsf(o2-c2)) * (1.0f/3.0f);

        clbuf[(size_t)n * NPIX + b * RWH + (yy - 8) * RW + px] = cl;

        // grad loss terms (center view's blocks only; same math as before)
        if (n == 24) {
            if (xx <= 246) {
                f2u q1 = *(const f2u*)(cbase + 4);
                float wx = __expf(-50.0f * (fabsf(cv.w-c0) + fabsf(q1.x-c1) + fabsf(q1.y-c2)));
                lx_acc += wx * fabsf(pred[pidx + 1] - p);
            }
            if (yy <= 246) {
                f4u r = *(const f4u*)(cbase + ROWF);
                float wy = __expf(-50.0f * (fabsf(r.x-c0) + fabsf(r.y-c1) + fabsf(r.z-c2)));
                ly_acc += wy * fabsf(pred[pidx + Wimg] - p);
            }
        }
    }

    if (n == 24) {
        #pragma unroll
        for (int off = 32; off > 0; off >>= 1) {
            lx_acc += __shfl_down(lx_acc, off);
            ly_acc += __shfl_down(ly_acc, off);
        }
        if ((tid & 63) == 0) {
            atomicAdd(acc + 1, (double)lx_acc);
            atomicAdd(acc + 2, (double)ly_acc);
        }
    }
}

// ===========================================================================
// Kernel B: one lane = one pixel. Reads its 49 cl (coalesced, stride NPIX),
// gauss + all-pairs stable rank + tail sum entirely in registers. Tie-break
// uses compile-time (m<n): cnt += (m<n) ? (bm>=bn) : (bm>bn) -- identical
// order to the packed (bits<<8)|(255-idx) u64 keys, 1 cmp/pair.
// ===========================================================================

__global__ __launch_bounds__(256) void rank_kernel(
    const float* __restrict__ clbuf, const float* __restrict__ y,
    const int* __restrict__ epoch_p, double* __restrict__ acc)
{
    __shared__ float sred[4];
    const int tid  = threadIdx.x;
    int gpix = blockIdx.x*256 + tid;     // 0..230399 ; block is batch-uniform
    int b    = gpix / RWH;
    int pix  = gpix - b*RWH;
    int ry   = pix / RW, rx = pix - ry*RW;
    int yy   = 8 + ry,   xx = 8 + rx;
    float yval = y[(b*Himg + yy)*Wimg + xx];
    const int epoch = *epoch_p;

    float cl[49];
    #pragma unroll
    for (int n = 0; n < 49; n++)
        cl[n] = clbuf[(size_t)n*NPIX + gpix];

    // angular gaussian (edge-replicated), exact tap order as reference
    float g[49];
    if (epoch > 0) {
        #pragma unroll
        for (int u = 0; u < 7; u++) {
            const int um1 = (u > 0) ? u-1 : 0;
            const int up1 = (u < 6) ? u+1 : 6;
            #pragma unroll
            for (int v = 0; v < 7; v++) {
                const int vm = (v > 0) ? v-1 : 0;
                const int vp = (v < 6) ? v+1 : 6;
                g[u*7+v] =
                    0.0751f*cl[um1*7+vm] + 0.1238f*cl[um1*7+v] + 0.0751f*cl[um1*7+vp] +
                    0.1238f*cl[u*7+vm]   + 0.2042f*cl[u*7+v]   + 0.1238f*cl[u*7+vp] +
                    0.0751f*cl[up1*7+vm] + 0.1238f*cl[up1*7+v] + 0.0751f*cl[up1*7+vp];
            }
        }
    } else {
        #pragma unroll
        for (int n = 0; n < 49; n++) g[n] = cl[n];
    }

    // stable-descending rank; keys >= 0 so u32 bits order == float order
    float tail = 0.0f;
    #pragma unroll
    for (int n = 0; n < 49; n++) {
        unsigned int bn = __float_as_uint(g[n]);
        int cnt = 0;
        #pragma unroll
        for (int m = 0; m < 49; m++) {
            if (m == n) continue;
            unsigned int bm = __float_as_uint(g[m]);
            cnt += ((m < n) ? (bm >= bn) : (bm > bn)) ? 1 : 0;
        }
        tail += ((float)cnt > yval) ? cl[n] : 0.0f;
    }
    float contrib = tail * (49.0f / (49.0f - yval));

    #pragma unroll
    for (int off = 32; off > 0; off >>= 1)
        contrib += __shfl_down(contrib, off);
    if ((tid & 63) == 0) sred[tid >> 6] = contrib;
    __syncthreads();
    if (tid == 0)
        atomicAdd(acc + 0, (double)(sred[0] + sred[1] + sred[2] + sred[3]));
}

// ===========================================================================
// FUSED FALLBACK (R3 kernel, proven pass) -- used only if ws_size too small
// ===========================================================================

__global__ __launch_bounds__(448, 4) void color_kernel(
    const float* __restrict__ pred, const float* __restrict__ x,
    const float* __restrict__ y, const int* __restrict__ epoch_p,
    double* __restrict__ acc)
{
    __shared__ float s_cl[64 * NVP];
    __shared__ float s_g [64 * NVP];
    __shared__ float sred[8];

    const int tid = threadIdx.x;
    const int pix = tid & 63;
    const int sub = __builtin_amdgcn_readfirstlane(tid >> 6);   // 0..6

    int lb  = (blockIdx.x & 7) * (NBLK/8) + (blockIdx.x >> 3);
    int pid = lb * 64 + pix;
    int b   = pid / RWH;
    int rem = pid - b * RWH;
    int ry  = rem / RW;
    int yy  = 8 + ry;
    int xx  = 8 + (rem - ry * RW);

    int pidx = (b * Himg + yy) * Wimg + xx;
    float p    = pred[pidx];
    float yval = y[pidx];
    const int epoch = *epoch_p;

    const float* xv    = x + (size_t)b * (49 * IMGF);
    const float* cbase = xv + (24 * IMGF) + (yy * Wimg + xx) * 3;
    f4u cv = *(const f4u*)cbase;
    float c0 = cv.x, c1 = cv.y, c2 = cv.z;

    float* mycl = s_cl + pix * NVP;
    float* myg  = s_g  + pix * NVP;

    int co[7]; float txv[7];
    #pragma unroll
    for (int vv = 0; vv < 7; vv++) {
        float cx = fminf(fmaxf((float)xx + p * (float)(vv-3), 0.0f), 255.0f);
        float x0f = floorf(cx);
        float tx = cx - x0f;
        int ix0 = (int)x0f;
        if (ix0 >= 255) { ix0 = 254; tx = 1.0f; }
        co[vv] = ix0 * 3; txv[vv] = tx;
    }

    float creg[7];
    {
        float cy = fminf(fmaxf((float)yy + p * (float)(sub-3), 0.0f), 255.0f);
        float y0f = floorf(cy);
        float ty = cy - y0f;
        int iy0 = (int)y0f;
        int iy1 = min(iy0+1, 255);
        int ro0 = iy0*ROWF, ro1 = iy1*ROWF;
        const float* vbase = xv + sub * 7 * IMGF;

        f4u a0[4], b0[4]; f2u a1[4], b1[4];

#define LOADV(VV, S) { \
        const float* s0p = vbase + (VV)*IMGF + ro0 + co[VV]; \
        const float* s1p = vbase + (VV)*IMGF + ro1 + co[VV]; \
        a0[S] = *(const f4u*)s0p;  a1[S] = *(const f2u*)(s0p + 4); \
        b0[S] = *(const f4u*)s1p;  b1[S] = *(const f2u*)(s1p + 4); }

        LOADV(0,0) LOADV(1,1) LOADV(2,2)
        __builtin_amdgcn_sched_barrier(0);

        #pragma unroll
        for (int vv = 0; vv < 7; vv++) {
            if (vv + 3 < 7) { LOADV(vv+3, (vv+3)&3) }
            __builtin_amdgcn_sched_barrier(0);
            const int S = vv & 3;
            float tx = txv[vv];
            float s00 = a0[S].x, s01 = a0[S].y, s02 = a0[S].z;
            float s03 = a0[S].w, s04 = a1[S].x, s05 = a1[S].y;
            float s10 = b0[S].x, s11 = b0[S].y, s12 = b0[S].z;
            float s13 = b0[S].w, s14 = b1[S].x, s15 = b1[S].y;
            float h0 = s00 + tx*(s03-s00);
            float h1 = s01 + tx*(s04-s01);
            float h2 = s02 + tx*(s05-s02);
            float k0 = s10 + tx*(s13-s10);
            float k1 = s11 + tx*(s14-s11);
            float k2 = s12 + tx*(s15-s12);
            float o0 = h0 + ty*(k0-h0);
            float o1 = h1 + ty*(k1-h1);
            float o2 = h2 + ty*(k2-h2);
            float cl = (fabsf(o0-c0)+fabsf(o1-c1)+fabsf(o2-c2)) * (1.0f/3.0f);
            creg[vv] = cl;
            mycl[sub*7 + vv] = cl;
            __builtin_amdgcn_sched_barrier(0);
        }
#undef LOADV
    }

    if (sub == 3) {
        float lx = 0.0f, ly = 0.0f;
        if (xx <= 246) {
            f4u q0 = *(const f4u*)cbase;
            f2u q1 = *(const f2u*)(cbase + 4);
            float wx = __expf(-50.0f * (fabsf(q0.w-c0) + fabsf(q1.x-c1) + fabsf(q1.y-c2)));
            lx = wx * fabsf(pred[pidx + 1] - p);
        }
        if (yy <= 246) {
            f4u r = *(const f4u*)(cbase + ROWF);
            float wy = __expf(-50.0f * (fabsf(r.x-c0) + fabsf(r.y-c1) + fabsf(r.z-c2)));
            ly = wy * fabsf(pred[pidx + Wimg] - p);
        }
        #pragma unroll
        for (int off = 32; off > 0; off >>= 1) {
            lx += __shfl_down(lx, off);
            ly += __shfl_down(ly, off);
        }
        if (pix == 0) {
            atomicAdd(acc + 1, (double)lx);
            atomicAdd(acc + 2, (double)ly);
        }
    }
    __syncthreads();

    if (epoch > 0) {
        const int um1 = (sub > 0) ? sub-1 : 0;
        const int up1 = (sub < 6) ? sub+1 : 6;
        const float* rm = mycl + um1*7;
        const float* rc = mycl + sub*7;
        const float* rp = mycl + up1*7;
        #pragma unroll
        for (int vv = 0; vv < 7; vv++) {
            const int vm = (vv > 0) ? vv-1 : 0;
            const int vp = (vv < 6) ? vv+1 : 6;
            myg[sub*7 + vv] =
                0.0751f*rm[vm] + 0.1238f*rm[vv] + 0.0751f*rm[vp] +
                0.1238f*rc[vm] + 0.2042f*rc[vv] + 0.1238f*rc[vp] +
                0.0751f*rp[vm] + 0.1238f*rp[vv] + 0.0751f*rp[vp];
        }
    }
    __syncthreads();

    const float* keyb = (epoch > 0) ? myg : mycl;

    f4a kv[13];
    #pragma unroll
    for (int i = 0; i < 13; i++)
        kv[i] = *(const f4a*)(keyb + 4*i);

    unsigned long long kn[7];
    int cnt[7];
    #pragma unroll
    for (int i = 0; i < 7; i++) {
        int n = sub*7 + i;
        unsigned int bb = __float_as_uint(keyb[n]);
        kn[i] = (((unsigned long long)bb) << 8) | (unsigned long long)(255 - n);
        cnt[i] = 0;
    }
    #pragma unroll
    for (int m = 0; m < NV; m++) {
        unsigned int bm = __float_as_uint(kv[m>>2][m&3]);
        unsigned long long km = (((unsigned long long)bm) << 8) | (unsigned long long)(255 - m);
        #pragma unroll
        for (int i = 0; i < 7; i++)
            cnt[i] += (km > kn[i]) ? 1 : 0;
    }
    float tail = 0.0f;
    #pragma unroll
    for (int i = 0; i < 7; i++)
        tail += ((float)cnt[i] > yval) ? creg[i] : 0.0f;
    float contrib = tail * (49.0f / (49.0f - yval));

    #pragma unroll
    for (int off = 32; off > 0; off >>= 1)
        contrib += __shfl_down(contrib, off);
    if (pix == 0) sred[sub] = contrib;
    __syncthreads();
    if (tid == 0) {
        double s = 0.0;
        #pragma unroll
        for (int i = 0; i < 7; i++) s += (double)sred[i];
        atomicAdd(acc + 0, s);
    }
}

__global__ void finalize_kernel(const double* __restrict__ acc,
                                float* __restrict__ out)
{
    double cl = acc[0] / 11289600.0;           // 4*49*240*240
    double gl = (acc[1] + acc[2]) / (2.0 * 229440.0);  // 4*240*239 each
    out[0] = (float)(cl + 0.1 * gl);
}

extern "C" void kernel_launch(void* const* d_in, const int* in_sizes, int n_in,
                              void* d_out, int out_size, void* d_ws, size_t ws_size,
                              hipStream_t stream)
{
    const float* pred  = (const float*)d_in[0];
    const float* x     = (const float*)d_in[1];
    const float* y     = (const float*)d_in[2];
    const int*   epoch = (const int*)d_in[3];
    double* acc  = (double*)d_ws;

    hipMemsetAsync(acc, 0, 3 * sizeof(double), stream);

    const size_t need = 256 + (size_t)NV * NPIX * sizeof(float);   // ~45.2 MB
    if (ws_size >= need) {
        float* clbuf = (float*)((char*)d_ws + 256);
        cl_kernel<<<TBLKS, 256, 0, stream>>>(pred, x, clbuf, acc);
        rank_kernel<<<NPIX/256, 256, 0, stream>>>(clbuf, y, epoch, acc);
    } else {
        color_kernel<<<NBLK, 448, 0, stream>>>(pred, x, y, epoch, acc);
    }
    finalize_kernel<<<1, 1, 0, stream>>>(acc, (float*)d_out);
}

// Round 8
// 353.991 us; speedup vs baseline: 1.4065x; 1.1868x over previous
//
#include <hip/hip_runtime.h>
#include <math.h>

#define NV    49
#define NVP   52
#define Himg  256
#define Wimg  256
#define RW    240
#define RWH   (RW*RW)          // 57600
#define NPIX  (4*RWH)          // 230400
#define ROWF  (Wimg*3)         // 768 floats per image row
#define IMGF  (Himg*Wimg*3)    // 196608 floats per view image
#define NBLK  (NPIX/64)        // 3600 blocks (fused fallback)

// staged-gather geometry (R8): 30 output rows/block, 960 threads, 45 staged
// rows = 139 KB LDS -> 1 block/CU but 15 waves/CU (47%) vs R7's 8 (19.7%).
#define HS2   30               // output rows per strip
#define NSTR2 (RW/HS2)         // 8 strips per (b,view)
#define TBLK2 (NSTR2*196)      // 1568 blocks = 8 * 196 (bijective XCD bands)
#define RSTG2 45               // staged source rows: [Y-7, Y+37], always in 1..255
#define LDSW  772              // padded LDS row stride (768+4); row step 3088B=193*16
#define CLTH  960              // threads per cl block (15 waves)

// 4B-aligned wide vector loads (gfx950 global loads legal at dword align)
typedef float f4u __attribute__((ext_vector_type(4), aligned(4)));
typedef float f2u __attribute__((ext_vector_type(2), aligned(4)));
typedef float f4a __attribute__((ext_vector_type(4), aligned(16)));

// ===========================================================================
// Kernel A (staged, wide): stage 45 full-width image rows in LDS (coalesced
// float4), bilinear-gather from LDS (no TA line-txns); lanes outside the
// +/-7-row jitter window (~1.4%) take the original global path.
// R7 proved the staging works but starved at 8 waves/CU; this geometry gives
// 15 waves/CU and halves staging bytes/pixel (45 rows serve 30, not 22->8).
// ===========================================================================

__global__ __launch_bounds__(CLTH) void cl_kernel(
    const float* __restrict__ pred, const float* __restrict__ x,
    float* __restrict__ clbuf, double* __restrict__ acc)
{
    __shared__ float tile[RSTG2 * LDSW];     // 138,960 B

    const int tid = threadIdx.x;

    // bijective XCD band swizzle: 1568 = 8 * 196
    int myblk = (blockIdx.x & 7) * (TBLK2/8) + (blockIdx.x >> 3);
    int q     = myblk / NSTR2;               // 0..195  (b*49 + n)
    int s     = myblk - q * NSTR2;           // 0..7
    int b     = q / NV;
    int n     = q - b * NV;
    int u     = n / 7, v = n - u * 7;
    int Y     = 8 + s * HS2;                 // first output row: 8..218
    int r0    = Y - 7;                       // staged rows r0..r0+44 (1..255)

    const float* xv = x + (size_t)b * (49 * IMGF);
    const float* ib = xv + n * IMGF;

    // ---- stage 45 source rows (full width) into LDS, coalesced ----
    {
        const float* src = ib + r0 * ROWF;
        for (int j = tid; j < RSTG2 * (ROWF/4); j += CLTH) {  // 8640/960 = 9
            int r  = j / (ROWF/4);
            int c4 = j - r * (ROWF/4);
            *(f4a*)&tile[r * LDSW + c4 * 4] = *(const f4a*)(src + j * 4);
        }
    }
    __syncthreads();

    // ---- compute 30x240 output pixels, 7.5 px/thread ----
    float lx_acc = 0.0f, ly_acc = 0.0f;

    for (int i = tid; i < HS2 * RW; i += CLTH) {
        int py = i / RW;
        int px = i - py * RW;
        int yy = Y + py;
        int xx = 8 + px;
        int pidx = (b * Himg + yy) * Wimg + xx;
        float p = pred[pidx];

        const float* cbase = xv + 24 * IMGF + (yy * Wimg + xx) * 3;
        f4u cv = *(const f4u*)cbase;         // center texel (in-bounds)
        float c0 = cv.x, c1 = cv.y, c2 = cv.z;

        // x interpolant
        float cx  = fminf(fmaxf((float)xx + p * (float)(v - 3), 0.0f), 255.0f);
        float x0f = floorf(cx);
        float tx  = cx - x0f;
        int ix0   = (int)x0f;
        if (ix0 >= 255) { ix0 = 254; tx = 1.0f; }
        // y interpolant
        float cy  = fminf(fmaxf((float)yy + p * (float)(u - 3), 0.0f), 255.0f);
        float y0f = floorf(cy);
        float ty  = cy - y0f;
        int iy0   = (int)y0f;
        int iy1   = min(iy0 + 1, 255);

        float s00, s01, s02, s03, s04, s05;
        float s10, s11, s12, s13, s14, s15;

        bool ok = (iy0 >= r0) && (iy1 <= r0 + RSTG2 - 1);
        if (ok) {
            int b0 = (iy0 - r0) * LDSW + ix0 * 3;
            int b1 = (iy1 - r0) * LDSW + ix0 * 3;
            s00 = tile[b0+0]; s01 = tile[b0+1]; s02 = tile[b0+2];
            s03 = tile[b0+3]; s04 = tile[b0+4]; s05 = tile[b0+5];
            s10 = tile[b1+0]; s11 = tile[b1+1]; s12 = tile[b1+2];
            s13 = tile[b1+3]; s14 = tile[b1+4]; s15 = tile[b1+5];
        } else {
            const float* s0p = ib + iy0 * ROWF + ix0 * 3;
            const float* s1p = ib + iy1 * ROWF + ix0 * 3;
            f4u a0 = *(const f4u*)s0p;  f2u a1 = *(const f2u*)(s0p + 4);
            f4u b0v = *(const f4u*)s1p; f2u b1v = *(const f2u*)(s1p + 4);
            s00 = a0.x;  s01 = a0.y;  s02 = a0.z;  s03 = a0.w;  s04 = a1.x;  s05 = a1.y;
            s10 = b0v.x; s11 = b0v.y; s12 = b0v.z; s13 = b0v.w; s14 = b1v.x; s15 = b1v.y;
        }

        float h0 = s00 + tx*(s03-s00);
        float h1 = s01 + tx*(s04-s01);
        float h2 = s02 + tx*(s05-s02);
        float k0 = s10 + tx*(s13-s10);
        float k1 = s11 + tx*(s14-s11);
        float k2 = s12 + tx*(s15-s12);
        float o0 = h0 + ty*(k0-h0);
        float o1 = h1 + ty*(k1-h1);
        float o2 = h2 + ty*(k2-h2);
        float cl = (fabsf(o0-c0)+fabsf(o1-c1)+fabsf(o2-c2)) * (1.0f/3.0f);

        clbuf[(size_t)n * NPIX + b * RWH + (yy - 8) * RW + px] = cl;

        // grad loss terms (center view's blocks only; same math as before)
        if (n == 24) {
            if (xx <= 246) {
                f2u q1 = *(const f2u*)(cbase + 4);
                float wx = __expf(-50.0f * (fabsf(cv.w-c0) + fabsf(q1.x-c1) + fabsf(q1.y-c2)));
                lx_acc += wx * fabsf(pred[pidx + 1] - p);
            }
            if (yy <= 246) {
                f4u r = *(const f4u*)(cbase + ROWF);
                float wy = __expf(-50.0f * (fabsf(r.x-c0) + fabsf(r.y-c1) + fabsf(r.z-c2)));
                ly_acc += wy * fabsf(pred[pidx + Wimg] - p);
            }
        }
    }

    if (n == 24) {
        #pragma unroll
        for (int off = 32; off > 0; off >>= 1) {
            lx_acc += __shfl_down(lx_acc, off);
            ly_acc += __shfl_down(ly_acc, off);
        }
        if ((tid & 63) == 0) {
            atomicAdd(acc + 1, (double)lx_acc);
            atomicAdd(acc + 2, (double)ly_acc);
        }
    }
}

// ===========================================================================
// Kernel B (rolling-window): computing g[49] from cl[49] held both arrays
// live (~115 VGPR -> scratch spill, ~65us by bench arithmetic). Now g is
// built row-by-row from a rolling 3-row (21-float) window; the tail sum
// reloads cl[n] from L2-hot clbuf in a separate phase gated by a 49-bit
// mask, so the reload never overlaps g's live range. Peak ~85 VGPR.
// ===========================================================================

#define GROW(DST, RM, RC, RP) { \
    _Pragma("unroll") \
    for (int vv = 0; vv < 7; vv++) { \
        const int vm = (vv > 0) ? vv-1 : 0; \
        const int vp = (vv < 6) ? vv+1 : 6; \
        (DST)[vv] = 0.0751f*(RM)[vm] + 0.1238f*(RM)[vv] + 0.0751f*(RM)[vp] + \
                    0.1238f*(RC)[vm] + 0.2042f*(RC)[vv] + 0.1238f*(RC)[vp] + \
                    0.0751f*(RP)[vm] + 0.1238f*(RP)[vv] + 0.0751f*(RP)[vp]; } }

__global__ __launch_bounds__(256) void rank_kernel(
    const float* __restrict__ clbuf, const float* __restrict__ y,
    const int* __restrict__ epoch_p, double* __restrict__ acc)
{
    __shared__ float sred[4];
    const int tid  = threadIdx.x;
    int gpix = blockIdx.x*256 + tid;     // 0..230399
    int b    = gpix / RWH;
    int pix  = gpix - b*RWH;
    int ry   = pix / RW, rx = pix - ry*RW;
    int yy   = 8 + ry,   xx = 8 + rx;
    float yval = y[(b*Himg + yy)*Wimg + xx];
    const int epoch = *epoch_p;

    float g[49];
    if (epoch > 0) {
        float wA[7], wB[7], wC[7];
        #pragma unroll
        for (int vv = 0; vv < 7; vv++) wA[vv] = clbuf[(size_t)vv*NPIX + gpix];        // row 0
        #pragma unroll
        for (int vv = 0; vv < 7; vv++) wB[vv] = clbuf[(size_t)(7+vv)*NPIX + gpix];    // row 1
        GROW(g + 0, wA, wA, wB)                                                       // u=0 (um1 clamp)
        #pragma unroll
        for (int vv = 0; vv < 7; vv++) wC[vv] = clbuf[(size_t)(14+vv)*NPIX + gpix];   // row 2
        GROW(g + 7, wA, wB, wC)                                                       // u=1
        #pragma unroll
        for (int uu = 2; uu <= 6; uu++) {
            #pragma unroll
            for (int vv = 0; vv < 7; vv++) { wA[vv] = wB[vv]; wB[vv] = wC[vv]; }
            if (uu < 6) {
                #pragma unroll
                for (int vv = 0; vv < 7; vv++)
                    wC[vv] = clbuf[(size_t)((uu+1)*7+vv)*NPIX + gpix];
            } else {
                #pragma unroll
                for (int vv = 0; vv < 7; vv++) wC[vv] = wB[vv];                       // up1 clamp
            }
            GROW(g + uu*7, wA, wB, wC)
        }
    } else {
        #pragma unroll
        for (int nn = 0; nn < 49; nn++)
            g[nn] = clbuf[(size_t)nn*NPIX + gpix];
    }

    // stable-descending rank; keys >= 0 so u32 bit order == float order;
    // tie-break (m<n) at compile time == packed (bits<<8)|(255-idx) u64 order
    unsigned long long sel = 0ull;
    #pragma unroll
    for (int nn = 0; nn < 49; nn++) {
        unsigned int bn = __float_as_uint(g[nn]);
        int cnt = 0;
        #pragma unroll
        for (int m = 0; m < 49; m++) {
            if (m == nn) continue;
            unsigned int bm = __float_as_uint(g[m]);
            cnt += ((m < nn) ? (bm >= bn) : (bm > bn)) ? 1 : 0;
        }
        if ((float)cnt > yval) sel |= (1ull << nn);
    }

    // separate reload phase (g dead by now): coalesced L2-hot reads
    float tail = 0.0f;
    #pragma unroll
    for (int nn = 0; nn < 49; nn++) {
        float clv = clbuf[(size_t)nn*NPIX + gpix];
        tail += ((sel >> nn) & 1ull) ? clv : 0.0f;
    }
    float contrib = tail * (49.0f / (49.0f - yval));

    #pragma unroll
    for (int off = 32; off > 0; off >>= 1)
        contrib += __shfl_down(contrib, off);
    if ((tid & 63) == 0) sred[tid >> 6] = contrib;
    __syncthreads();
    if (tid == 0)
        atomicAdd(acc + 0, (double)(sred[0] + sred[1] + sred[2] + sred[3]));
}

// ===========================================================================
// FUSED FALLBACK (R3 kernel, proven pass) -- used only if ws_size too small
// ===========================================================================

__global__ __launch_bounds__(448, 4) void color_kernel(
    const float* __restrict__ pred, const float* __restrict__ x,
    const float* __restrict__ y, const int* __restrict__ epoch_p,
    double* __restrict__ acc)
{
    __shared__ float s_cl[64 * NVP];
    __shared__ float s_g [64 * NVP];
    __shared__ float sred[8];

    const int tid = threadIdx.x;
    const int pix = tid & 63;
    const int sub = __builtin_amdgcn_readfirstlane(tid >> 6);   // 0..6

    int lb  = (blockIdx.x & 7) * (NBLK/8) + (blockIdx.x >> 3);
    int pid = lb * 64 + pix;
    int b   = pid / RWH;
    int rem = pid - b * RWH;
    int ry  = rem / RW;
    int yy  = 8 + ry;
    int xx  = 8 + (rem - ry * RW);

    int pidx = (b * Himg + yy) * Wimg + xx;
    float p    = pred[pidx];
    float yval = y[pidx];
    const int epoch = *epoch_p;

    const float* xv    = x + (size_t)b * (49 * IMGF);
    const float* cbase = xv + (24 * IMGF) + (yy * Wimg + xx) * 3;
    f4u cv = *(const f4u*)cbase;
    float c0 = cv.x, c1 = cv.y, c2 = cv.z;

    float* mycl = s_cl + pix * NVP;
    float* myg  = s_g  + pix * NVP;

    int co[7]; float txv[7];
    #pragma unroll
    for (int vv = 0; vv < 7; vv++) {
        float cx = fminf(fmaxf((float)xx + p * (float)(vv-3), 0.0f), 255.0f);
        float x0f = floorf(cx);
        float tx = cx - x0f;
        int ix0 = (int)x0f;
        if (ix0 >= 255) { ix0 = 254; tx = 1.0f; }
        co[vv] = ix0 * 3; txv[vv] = tx;
    }

    float creg[7];
    {
        float cy = fminf(fmaxf((float)yy + p * (float)(sub-3), 0.0f), 255.0f);
        float y0f = floorf(cy);
        float ty = cy - y0f;
        int iy0 = (int)y0f;
        int iy1 = min(iy0+1, 255);
        int ro0 = iy0*ROWF, ro1 = iy1*ROWF;
        const float* vbase = xv + sub * 7 * IMGF;

        f4u a0[4], b0[4]; f2u a1[4], b1[4];

#define LOADV(VV, S) { \
        const float* s0p = vbase + (VV)*IMGF + ro0 + co[VV]; \
        const float* s1p = vbase + (VV)*IMGF + ro1 + co[VV]; \
        a0[S] = *(const f4u*)s0p;  a1[S] = *(const f2u*)(s0p + 4); \
        b0[S] = *(const f4u*)s1p;  b1[S] = *(const f2u*)(s1p + 4); }

        LOADV(0,0) LOADV(1,1) LOADV(2,2)
        __builtin_amdgcn_sched_barrier(0);

        #pragma unroll
        for (int vv = 0; vv < 7; vv++) {
            if (vv + 3 < 7) { LOADV(vv+3, (vv+3)&3) }
            __builtin_amdgcn_sched_barrier(0);
            const int S = vv & 3;
            float tx = txv[vv];
            float s00 = a0[S].x, s01 = a0[S].y, s02 = a0[S].z;
            float s03 = a0[S].w, s04 = a1[S].x, s05 = a1[S].y;
            float s10 = b0[S].x, s11 = b0[S].y, s12 = b0[S].z;
            float s13 = b0[S].w, s14 = b1[S].x, s15 = b1[S].y;
            float h0 = s00 + tx*(s03-s00);
            float h1 = s01 + tx*(s04-s01);
            float h2 = s02 + tx*(s05-s02);
            float k0 = s10 + tx*(s13-s10);
            float k1 = s11 + tx*(s14-s11);
            float k2 = s12 + tx*(s15-s12);
            float o0 = h0 + ty*(k0-h0);
            float o1 = h1 + ty*(k1-h1);
            float o2 = h2 + ty*(k2-h2);
            float cl = (fabsf(o0-c0)+fabsf(o1-c1)+fabsf(o2-c2)) * (1.0f/3.0f);
            creg[vv] = cl;
            mycl[sub*7 + vv] = cl;
            __builtin_amdgcn_sched_barrier(0);
        }
#undef LOADV
    }

    if (sub == 3) {
        float lx = 0.0f, ly = 0.0f;
        if (xx <= 246) {
            f4u q0 = *(const f4u*)cbase;
            f2u q1 = *(const f2u*)(cbase + 4);
            float wx = __expf(-50.0f * (fabsf(q0.w-c0) + fabsf(q1.x-c1) + fabsf(q1.y-c2)));
            lx = wx * fabsf(pred[pidx + 1] - p);
        }
        if (yy <= 246) {
            f4u r = *(const f4u*)(cbase + ROWF);
            float wy = __expf(-50.0f * (fabsf(r.x-c0) + fabsf(r.y-c1) + fabsf(r.z-c2)));
            ly = wy * fabsf(pred[pidx + Wimg] - p);
        }
        #pragma unroll
        for (int off = 32; off > 0; off >>= 1) {
            lx += __shfl_down(lx, off);
            ly += __shfl_down(ly, off);
        }
        if (pix == 0) {
            atomicAdd(acc + 1, (double)lx);
            atomicAdd(acc + 2, (double)ly);
        }
    }
    __syncthreads();

    if (epoch > 0) {
        const int um1 = (sub > 0) ? sub-1 : 0;
        const int up1 = (sub < 6) ? sub+1 : 6;
        const float* rm = mycl + um1*7;
        const float* rc = mycl + sub*7;
        const float* rp = mycl + up1*7;
        #pragma unroll
        for (int vv = 0; vv < 7; vv++) {
            const int vm = (vv > 0) ? vv-1 : 0;
            const int vp = (vv < 6) ? vv+1 : 6;
            myg[sub*7 + vv] =
                0.0751f*rm[vm] + 0.1238f*rm[vv] + 0.0751f*rm[vp] +
                0.1238f*rc[vm] + 0.2042f*rc[vv] + 0.1238f*rc[vp] +
                0.0751f*rp[vm] + 0.1238f*rp[vv] + 0.0751f*rp[vp];
        }
    }
    __syncthreads();

    const float* keyb = (epoch > 0) ? myg : mycl;

    f4a kv[13];
    #pragma unroll
    for (int i = 0; i < 13; i++)
        kv[i] = *(const f4a*)(keyb + 4*i);

    unsigned long long kn[7];
    int cnt[7];
    #pragma unroll
    for (int i = 0; i < 7; i++) {
        int n = sub*7 + i;
        unsigned int bb = __float_as_uint(keyb[n]);
        kn[i] = (((unsigned long long)bb) << 8) | (unsigned long long)(255 - n);
        cnt[i] = 0;
    }
    #pragma unroll
    for (int m = 0; m < NV; m++) {
        unsigned int bm = __float_as_uint(kv[m>>2][m&3]);
        unsigned long long km = (((unsigned long long)bm) << 8) | (unsigned long long)(255 - m);
        #pragma unroll
        for (int i = 0; i < 7; i++)
            cnt[i] += (km > kn[i]) ? 1 : 0;
    }
    float tail = 0.0f;
    #pragma unroll
    for (int i = 0; i < 7; i++)
        tail += ((float)cnt[i] > yval) ? creg[i] : 0.0f;
    float contrib = tail * (49.0f / (49.0f - yval));

    #pragma unroll
    for (int off = 32; off > 0; off >>= 1)
        contrib += __shfl_down(contrib, off);
    if (pix == 0) sred[sub] = contrib;
    __syncthreads();
    if (tid == 0) {
        double s = 0.0;
        #pragma unroll
        for (int i = 0; i < 7; i++) s += (double)sred[i];
        atomicAdd(acc + 0, s);
    }
}

__global__ void finalize_kernel(const double* __restrict__ acc,
                                float* __restrict__ out)
{
    double cl = acc[0] / 11289600.0;           // 4*49*240*240
    double gl = (acc[1] + acc[2]) / (2.0 * 229440.0);  // 4*240*239 each
    out[0] = (float)(cl + 0.1 * gl);
}

extern "C" void kernel_launch(void* const* d_in, const int* in_sizes, int n_in,
                              void* d_out, int out_size, void* d_ws, size_t ws_size,
                              hipStream_t stream)
{
    const float* pred  = (const float*)d_in[0];
    const float* x     = (const float*)d_in[1];
    const float* y     = (const float*)d_in[2];
    const int*   epoch = (const int*)d_in[3];
    double* acc  = (double*)d_ws;

    hipMemsetAsync(acc, 0, 3 * sizeof(double), stream);

    const size_t need = 256 + (size_t)NV * NPIX * sizeof(float);   // ~45.2 MB
    if (ws_size >= need) {
        float* clbuf = (float*)((char*)d_ws + 256);
        cl_kernel<<<TBLK2, CLTH, 0, stream>>>(pred, x, clbuf, acc);
        rank_kernel<<<NPIX/256, 256, 0, stream>>>(clbuf, y, epoch, acc);
    } else {
        color_kernel<<<NBLK, 448, 0, stream>>>(pred, x, y, epoch, acc);
    }
    finalize_kernel<<<1, 1, 0, stream>>>(acc, (float*)d_out);
}